// Round 2
// baseline (1982.183 us; speedup 1.0000x reference)
//
#include <hip/hip_runtime.h>
#include <math.h>

#define NN 10000
#define IN_DIM 1000
#define HID 256
#define OUT_DIM 2

// ---------------- degree / CSR build ----------------

__global__ void k_zero_deg(int* deg, int n) {
    int i = blockIdx.x * 256 + threadIdx.x;
    if (i < n) deg[i] = 0;
}

__global__ void k_count(const int* __restrict__ dst, int E, int* __restrict__ deg) {
    int e = blockIdx.x * 256 + threadIdx.x;
    if (e < E) atomicAdd(&deg[dst[e]], 1);
}

__global__ void k_dinv(const int* __restrict__ deg, float* __restrict__ dinv, int n) {
    int i = blockIdx.x * 256 + threadIdx.x;
    if (i < n) dinv[i] = rsqrtf(1.0f + (float)deg[i]);   // self-loop => deg>=1
}

// single-block exclusive scan of deg -> offs, cursor
__global__ void k_scan(const int* __restrict__ deg, int* __restrict__ offs,
                       int* __restrict__ cursor, int n, int E) {
    __shared__ int part[256];
    int t = threadIdx.x;
    int chunk = (n + 255) / 256;
    int lo = t * chunk;
    int hi = lo + chunk; if (hi > n) hi = n;
    int s = 0;
    for (int i = lo; i < hi; i++) s += deg[i];
    part[t] = s;
    __syncthreads();
    if (t == 0) {
        int run = 0;
        for (int i = 0; i < 256; i++) { int tmp = part[i]; part[i] = run; run += tmp; }
    }
    __syncthreads();
    int base = part[t];
    for (int i = lo; i < hi; i++) { offs[i] = base; cursor[i] = base; base += deg[i]; }
    if (t == 0) offs[n] = E;
}

__global__ void k_fill(const int* __restrict__ src, const int* __restrict__ dst, int E,
                       int* __restrict__ cursor, int* __restrict__ csr) {
    int e = blockIdx.x * 256 + threadIdx.x;
    if (e < E) {
        int p = atomicAdd(&cursor[dst[e]], 1);
        csr[p] = src[e];
    }
}

// ---------------- GEMM1 v3: split-K into per-z PARTIAL buffers (no atomics) ---------
// Tile 128x128, BK=16, 256 threads (16x16), dbuf LDS, 8x8 micro-tile.
// Partials: C_part = C + z * M*N (contiguous), reduced by k_reduce afterwards.

#define G1_BM 128
#define G1_BN 128
#define G1_BK 16
#define G1_LDA (G1_BM + 4)   // 132 floats
#define G1_LDB (G1_BN + 4)

__global__ __launch_bounds__(256, 4) void k_gemm1(const float* __restrict__ A,
                                                  const float* __restrict__ B,
                                                  float* __restrict__ C,
                                                  int M, int K, int N, int kchunk) {
    __shared__ __align__(16) float As[2][G1_BK][G1_LDA];
    __shared__ __align__(16) float Bs[2][G1_BK][G1_LDB];

    const int tid = threadIdx.x;
    const int tx = tid & 15, ty = tid >> 4;
    const int row0 = blockIdx.y * G1_BM, col0 = blockIdx.x * G1_BN;
    const int kbeg = blockIdx.z * kchunk;
    const int kend = (kbeg + kchunk < K) ? (kbeg + kchunk) : K;
    const int T = (kend - kbeg + G1_BK - 1) / G1_BK;

    float* __restrict__ Cp = C + (size_t)blockIdx.z * M * N;

    const int arow = tid >> 2;          // 0..63 (+64 for r=1)
    const int ak4  = (tid & 3) * 4;     // k offset within tile
    const int bkk  = tid >> 5;          // 0..7 (+8 for r=1)
    const int bcg  = (tid & 31) * 4;    // col offset within tile

    float4 aR[2], bR[2];
    float acc[8][8];
    #pragma unroll
    for (int i = 0; i < 8; i++)
        #pragma unroll
        for (int j = 0; j < 8; j++) acc[i][j] = 0.0f;

    auto loadregs = [&](int t) {
        const int k0 = kbeg + t * G1_BK;
        #pragma unroll
        for (int r = 0; r < 2; r++) {
            int row = row0 + arow + 64 * r;
            int k = k0 + ak4;
            if (row < M && k < kend) aR[r] = *(const float4*)&A[(size_t)row * K + k];
            else                     aR[r] = make_float4(0.f, 0.f, 0.f, 0.f);
        }
        #pragma unroll
        for (int r = 0; r < 2; r++) {
            int k = k0 + bkk + 8 * r;
            if (k < kend) bR[r] = *(const float4*)&B[(size_t)k * N + col0 + bcg];
            else          bR[r] = make_float4(0.f, 0.f, 0.f, 0.f);
        }
    };

    auto storelds = [&](int buf) {
        #pragma unroll
        for (int r = 0; r < 2; r++) {
            int row = arow + 64 * r;
            As[buf][ak4 + 0][row] = aR[r].x;
            As[buf][ak4 + 1][row] = aR[r].y;
            As[buf][ak4 + 2][row] = aR[r].z;
            As[buf][ak4 + 3][row] = aR[r].w;
            *(float4*)&Bs[buf][bkk + 8 * r][bcg] = bR[r];
        }
    };

    loadregs(0);
    storelds(0);
    __syncthreads();

    for (int t = 0; t < T; t++) {
        const int cur = t & 1;
        if (t + 1 < T) loadregs(t + 1);
        #pragma unroll
        for (int kk = 0; kk < G1_BK; kk++) {
            float4 a0 = *(const float4*)&As[cur][kk][4 * ty];
            float4 a1 = *(const float4*)&As[cur][kk][64 + 4 * ty];
            float4 b0 = *(const float4*)&Bs[cur][kk][4 * tx];
            float4 b1 = *(const float4*)&Bs[cur][kk][64 + 4 * tx];
            float av[8] = {a0.x, a0.y, a0.z, a0.w, a1.x, a1.y, a1.z, a1.w};
            float bv[8] = {b0.x, b0.y, b0.z, b0.w, b1.x, b1.y, b1.z, b1.w};
            #pragma unroll
            for (int i = 0; i < 8; i++)
                #pragma unroll
                for (int j = 0; j < 8; j++)
                    acc[i][j] += av[i] * bv[j];
        }
        if (t + 1 < T) storelds((t + 1) & 1);
        __syncthreads();
    }

    // plain vectorized stores into this z's partial buffer
    #pragma unroll
    for (int i = 0; i < 8; i++) {
        int row = row0 + 4 * ty + (i >> 2) * 64 + (i & 3);
        if (row < M) {
            float4 v0 = {acc[i][0], acc[i][1], acc[i][2], acc[i][3]};
            float4 v1 = {acc[i][4], acc[i][5], acc[i][6], acc[i][7]};
            *(float4*)&Cp[(size_t)row * N + col0 + 4 * tx]      = v0;
            *(float4*)&Cp[(size_t)row * N + col0 + 64 + 4 * tx] = v1;
        }
    }
}

// ---------------- reduce split-K partials: p0 += p1 (+ p2 + p3) ----------------

__global__ __launch_bounds__(256) void k_reduce(float4* __restrict__ p0,
                                                const float4* __restrict__ p1,
                                                const float4* __restrict__ p2,
                                                const float4* __restrict__ p3,
                                                int n4, int S) {
    int i = blockIdx.x * 256 + threadIdx.x;
    if (i >= n4) return;
    float4 a = p0[i], b = p1[i];
    float4 r;
    r.x = a.x + b.x; r.y = a.y + b.y; r.z = a.z + b.z; r.w = a.w + b.w;
    if (S == 4) {
        float4 c = p2[i], d = p3[i];
        r.x += c.x + d.x; r.y += c.y + d.y; r.z += c.z + d.z; r.w += c.w + d.w;
    }
    p0[i] = r;
}

// ---------------- aggregation 1 + bias + relu (block per node, thread per dim) -------

__global__ __launch_bounds__(256) void k_agg1(const float* __restrict__ xw1,
                                              const int* __restrict__ offs,
                                              const int* __restrict__ csr,
                                              const float* __restrict__ dinv,
                                              const float* __restrict__ b1,
                                              float* __restrict__ h) {
    int i = blockIdx.x;
    int t = threadIdx.x;
    float di = dinv[i];
    float acc = di * xw1[i * HID + t];          // self-loop (factor di applied at end)
    int s0 = offs[i], s1 = offs[i + 1];
    for (int e = s0; e < s1; e++) {
        int s = csr[e];
        acc += dinv[s] * xw1[s * HID + t];
    }
    float v = di * acc + b1[t];
    h[i * HID + t] = fmaxf(v, 0.0f);
}

// ---------------- GEMM2 (wave per row) + self-loop epilogue into emb ----------------

__global__ __launch_bounds__(256) void k_gemm2(const float* __restrict__ h,
                                               const float* __restrict__ W2,
                                               const float* __restrict__ b2,
                                               const float* __restrict__ dinv,
                                               float* __restrict__ hw2,
                                               float* __restrict__ emb, int n) {
    int w = threadIdx.x >> 6, l = threadIdx.x & 63;
    int row = blockIdx.x * 4 + w;
    if (row >= n) return;
    float4 hv = *(const float4*)&h[row * HID + l * 4];
    // W2 row-major [256][2]; lane l covers k=4l..4l+3 -> floats 8l..8l+7
    float4 w0 = *(const float4*)&W2[l * 8];
    float4 w1 = *(const float4*)&W2[l * 8 + 4];
    float a0 = hv.x * w0.x + hv.y * w0.z + hv.z * w1.x + hv.w * w1.z;
    float a1 = hv.x * w0.y + hv.y * w0.w + hv.z * w1.y + hv.w * w1.w;
    #pragma unroll
    for (int off = 32; off; off >>= 1) {
        a0 += __shfl_down(a0, off);
        a1 += __shfl_down(a1, off);
    }
    if (l == 0) {
        hw2[row * 2] = a0;
        hw2[row * 2 + 1] = a1;
        float di = dinv[row];
        emb[row * 2]     = di * di * a0 + b2[0];
        emb[row * 2 + 1] = di * di * a1 + b2[1];
    }
}

// ---------------- aggregation 2 (wave per node, accumulate into emb) ----------------

__global__ __launch_bounds__(256) void k_agg2(const float* __restrict__ hw2,
                                              const int* __restrict__ offs,
                                              const int* __restrict__ csr,
                                              const float* __restrict__ dinv,
                                              float* __restrict__ emb, int n) {
    int w = threadIdx.x >> 6, l = threadIdx.x & 63;
    int i = blockIdx.x * 4 + w;
    if (i >= n) return;
    int s0 = offs[i], s1 = offs[i + 1];
    float a0 = 0.0f, a1 = 0.0f;
    for (int e = s0 + l; e < s1; e += 64) {
        int s = csr[e];
        float ds = dinv[s];
        a0 += ds * hw2[s * 2];
        a1 += ds * hw2[s * 2 + 1];
    }
    #pragma unroll
    for (int off = 32; off; off >>= 1) {
        a0 += __shfl_down(a0, off);
        a1 += __shfl_down(a1, off);
    }
    if (l == 0) {
        float di = dinv[i];
        emb[i * 2]     += di * a0;   // only this wave touches node i
        emb[i * 2 + 1] += di * a1;
    }
}

// ---------------- q = 1/(1 + 0.5*dist(e_i, e_j)), row-major [n][n] ----------------

__global__ __launch_bounds__(256) void k_q(const float* __restrict__ emb,
                                           float* __restrict__ q, int n) {
    int i = blockIdx.y;
    int j0 = (blockIdx.x * 256 + threadIdx.x) * 4;
    if (j0 >= n) return;
    float2 ei = *(const float2*)&emb[i * 2];
    float4 e01 = *(const float4*)&emb[j0 * 2];
    float4 e23 = *(const float4*)&emb[j0 * 2 + 4];
    float4 out;
    {
        float dx = ei.x - e01.x, dy = ei.y - e01.y;
        out.x = 1.0f / (1.0f + 0.5f * sqrtf(dx * dx + dy * dy));
    }
    {
        float dx = ei.x - e01.z, dy = ei.y - e01.w;
        out.y = 1.0f / (1.0f + 0.5f * sqrtf(dx * dx + dy * dy));
    }
    {
        float dx = ei.x - e23.x, dy = ei.y - e23.y;
        out.z = 1.0f / (1.0f + 0.5f * sqrtf(dx * dx + dy * dy));
    }
    {
        float dx = ei.x - e23.z, dy = ei.y - e23.w;
        out.w = 1.0f / (1.0f + 0.5f * sqrtf(dx * dx + dy * dy));
    }
    *(float4*)&q[(size_t)i * n + j0] = out;
}

// ---------------- launcher ----------------

extern "C" void kernel_launch(void* const* d_in, const int* in_sizes, int n_in,
                              void* d_out, int out_size, void* d_ws, size_t ws_size,
                              hipStream_t stream) {
    const float* features = (const float*)d_in[0];
    const int*   edge_index = (const int*)d_in[1];
    const float* W1 = (const float*)d_in[2];
    const float* b1 = (const float*)d_in[3];
    const float* W2 = (const float*)d_in[4];
    const float* b2 = (const float*)d_in[5];

    const int n = NN;
    const int E = in_sizes[1] / 2;
    const int* src = edge_index;
    const int* dst = edge_index + E;

    char* ws = (char*)d_ws;
    int*   deg    = (int*)ws;   ws += 40000;
    float* dinv   = (float*)ws; ws += 40000;
    int*   offs   = (int*)ws;   ws += 40016;          // n+1, padded to 16B
    int*   cursor = (int*)ws;   ws += 40000;
    int*   csr    = (int*)ws;   ws += (size_t)E * 4;  // 640 KB

    const size_t matElems = (size_t)NN * HID;          // 2.56M floats = 10.24 MB
    const size_t used     = (size_t)(ws - (char*)d_ws);

    // split-K partials are CONTIGUOUS starting at xw1:
    //   part0 = xw1, part1 (aliased by h after reduce), part2 (aliased by hw2), part3
    int S = (ws_size >= used + 4 * matElems * 4 + 16) ? 4 : 2;

    float* xw1 = (float*)ws;                 // part0
    float* h   = xw1 + matElems;             // part1 (dead after reduce -> reused as h)
    float* hw2 = xw1 + 2 * matElems;         // part2 region start (dead after reduce)

    float* emb = (float*)d_out;                 // [n,2]
    float* q   = (float*)d_out + (size_t)n * OUT_DIM;  // [n,n]

    k_zero_deg<<<(n + 255) / 256, 256, 0, stream>>>(deg, n);
    k_count<<<(E + 255) / 256, 256, 0, stream>>>(dst, E, deg);
    k_dinv<<<(n + 255) / 256, 256, 0, stream>>>(deg, dinv, n);
    k_scan<<<1, 256, 0, stream>>>(deg, offs, cursor, n, E);
    k_fill<<<(E + 255) / 256, 256, 0, stream>>>(src, dst, E, cursor, csr);

    // split-K GEMM into partial buffers, then reduce into xw1 (part0)
    int kchunk = (IN_DIM + S - 1) / S;
    k_gemm1<<<dim3(HID / G1_BN, (n + G1_BM - 1) / G1_BM, S), 256, 0, stream>>>(
        features, W1, xw1, n, IN_DIM, HID, kchunk);

    int n4 = (int)(matElems / 4);
    k_reduce<<<(n4 + 255) / 256, 256, 0, stream>>>(
        (float4*)xw1, (const float4*)(xw1 + matElems),
        (const float4*)(xw1 + 2 * matElems), (const float4*)(xw1 + 3 * matElems),
        n4, S);

    k_agg1<<<n, HID, 0, stream>>>(xw1, offs, csr, dinv, b1, h);
    k_gemm2<<<(n + 3) / 4, 256, 0, stream>>>(h, W2, b2, dinv, hw2, emb, n);
    k_agg2<<<(n + 3) / 4, 256, 0, stream>>>(hw2, offs, csr, dinv, emb, n);

    k_q<<<dim3((n + 1023) / 1024, n), 256, 0, stream>>>(emb, q, n);
}

// Round 3
// 674.662 us; speedup vs baseline: 2.9380x; 2.9380x over previous
//
#include <hip/hip_runtime.h>
#include <math.h>

#define NN 10000
#define IN_DIM 1000
#define HID 256
#define OUT_DIM 2

// ---------------- degree / CSR build ----------------

__global__ void k_zero_deg(int* deg, int n) {
    int i = blockIdx.x * 256 + threadIdx.x;
    if (i < n) deg[i] = 0;
}

__global__ void k_count(const int* __restrict__ dst, int E, int* __restrict__ deg) {
    int e = blockIdx.x * 256 + threadIdx.x;
    if (e < E) atomicAdd(&deg[dst[e]], 1);
}

__global__ void k_dinv(const int* __restrict__ deg, float* __restrict__ dinv, int n) {
    int i = blockIdx.x * 256 + threadIdx.x;
    if (i < n) dinv[i] = rsqrtf(1.0f + (float)deg[i]);   // self-loop => deg>=1
}

// single-block exclusive scan of deg -> offs, cursor
__global__ void k_scan(const int* __restrict__ deg, int* __restrict__ offs,
                       int* __restrict__ cursor, int n, int E) {
    __shared__ int part[256];
    int t = threadIdx.x;
    int chunk = (n + 255) / 256;
    int lo = t * chunk;
    int hi = lo + chunk; if (hi > n) hi = n;
    int s = 0;
    for (int i = lo; i < hi; i++) s += deg[i];
    part[t] = s;
    __syncthreads();
    if (t == 0) {
        int run = 0;
        for (int i = 0; i < 256; i++) { int tmp = part[i]; part[i] = run; run += tmp; }
    }
    __syncthreads();
    int base = part[t];
    for (int i = lo; i < hi; i++) { offs[i] = base; cursor[i] = base; base += deg[i]; }
    if (t == 0) offs[n] = E;
}

__global__ void k_fill(const int* __restrict__ src, const int* __restrict__ dst, int E,
                       int* __restrict__ cursor, int* __restrict__ csr) {
    int e = blockIdx.x * 256 + threadIdx.x;
    if (e < E) {
        int p = atomicAdd(&cursor[dst[e]], 1);
        csr[p] = src[e];
    }
}

// ---------------- GEMM1 v4: split-K partials, dbuf LDS, SPILL-PROOF 8x4 micro -------
// Tile 128x64, BK=16, 256 threads (16x16). acc[8][4]=32 VGPR -> ~72 total, no clamp.
// Partials: C_part = C + z * M*N (contiguous), reduced by k_reduce afterwards.

#define G1_BM 128
#define G1_BN 64
#define G1_BK 16
#define G1_LDA (G1_BM + 4)   // 132 floats
#define G1_LDB (G1_BN + 4)   // 68 floats

__global__ __launch_bounds__(256) void k_gemm1(const float* __restrict__ A,
                                               const float* __restrict__ B,
                                               float* __restrict__ C,
                                               int M, int K, int N, int kchunk) {
    __shared__ __align__(16) float As[2][G1_BK][G1_LDA];
    __shared__ __align__(16) float Bs[2][G1_BK][G1_LDB];

    const int tid = threadIdx.x;
    const int tx = tid & 15, ty = tid >> 4;
    const int row0 = blockIdx.y * G1_BM, col0 = blockIdx.x * G1_BN;
    const int kbeg = blockIdx.z * kchunk;
    const int kend = (kbeg + kchunk < K) ? (kbeg + kchunk) : K;
    const int T = (kend - kbeg + G1_BK - 1) / G1_BK;

    float* __restrict__ Cp = C + (size_t)blockIdx.z * M * N;

    // staging maps
    const int arow = tid >> 2;          // 0..63 (+64 for r=1)
    const int ak4  = (tid & 3) * 4;     // k offset within tile (0,4,8,12)
    const int bkk  = tid >> 4;          // 0..15
    const int bcg  = (tid & 15) * 4;    // col offset within tile

    float4 aR[2], bR;
    float acc[8][4];
    #pragma unroll
    for (int i = 0; i < 8; i++)
        #pragma unroll
        for (int j = 0; j < 4; j++) acc[i][j] = 0.0f;

    auto loadregs = [&](int t) {
        const int k0 = kbeg + t * G1_BK;
        #pragma unroll
        for (int r = 0; r < 2; r++) {
            int row = row0 + arow + 64 * r;
            int k = k0 + ak4;
            if (row < M && k < kend) aR[r] = *(const float4*)&A[(size_t)row * K + k];
            else                     aR[r] = make_float4(0.f, 0.f, 0.f, 0.f);
        }
        {
            int k = k0 + bkk;
            if (k < kend) bR = *(const float4*)&B[(size_t)k * N + col0 + bcg];
            else          bR = make_float4(0.f, 0.f, 0.f, 0.f);
        }
    };

    auto storelds = [&](int buf) {
        #pragma unroll
        for (int r = 0; r < 2; r++) {
            int row = arow + 64 * r;
            As[buf][ak4 + 0][row] = aR[r].x;
            As[buf][ak4 + 1][row] = aR[r].y;
            As[buf][ak4 + 2][row] = aR[r].z;
            As[buf][ak4 + 3][row] = aR[r].w;
        }
        *(float4*)&Bs[buf][bkk][bcg] = bR;
    };

    loadregs(0);
    storelds(0);
    __syncthreads();

    for (int t = 0; t < T; t++) {
        const int cur = t & 1;
        if (t + 1 < T) loadregs(t + 1);
        #pragma unroll
        for (int kk = 0; kk < G1_BK; kk++) {
            float4 a0 = *(const float4*)&As[cur][kk][4 * ty];
            float4 a1 = *(const float4*)&As[cur][kk][64 + 4 * ty];
            float4 b  = *(const float4*)&Bs[cur][kk][4 * tx];
            float av[8] = {a0.x, a0.y, a0.z, a0.w, a1.x, a1.y, a1.z, a1.w};
            float bv[4] = {b.x, b.y, b.z, b.w};
            #pragma unroll
            for (int i = 0; i < 8; i++)
                #pragma unroll
                for (int j = 0; j < 4; j++)
                    acc[i][j] += av[i] * bv[j];
        }
        if (t + 1 < T) storelds((t + 1) & 1);
        __syncthreads();
    }

    // plain vectorized stores into this z's partial buffer
    #pragma unroll
    for (int i = 0; i < 8; i++) {
        int row = row0 + 4 * ty + (i >> 2) * 64 + (i & 3);
        if (row < M) {
            float4 v = {acc[i][0], acc[i][1], acc[i][2], acc[i][3]};
            *(float4*)&Cp[(size_t)row * N + col0 + 4 * tx] = v;
        }
    }
}

// ---------------- reduce split-K partials: p0 += p1 (+ p2 + p3) ----------------

__global__ __launch_bounds__(256) void k_reduce(float4* __restrict__ p0,
                                                const float4* __restrict__ p1,
                                                const float4* __restrict__ p2,
                                                const float4* __restrict__ p3,
                                                int n4, int S) {
    int i = blockIdx.x * 256 + threadIdx.x;
    if (i >= n4) return;
    float4 a = p0[i], b = p1[i];
    float4 r;
    r.x = a.x + b.x; r.y = a.y + b.y; r.z = a.z + b.z; r.w = a.w + b.w;
    if (S == 4) {
        float4 c = p2[i], d = p3[i];
        r.x += c.x + d.x; r.y += c.y + d.y; r.z += c.z + d.z; r.w += c.w + d.w;
    }
    p0[i] = r;
}

// ---------------- aggregation 1 + bias + relu (block per node, thread per dim) -------

__global__ __launch_bounds__(256) void k_agg1(const float* __restrict__ xw1,
                                              const int* __restrict__ offs,
                                              const int* __restrict__ csr,
                                              const float* __restrict__ dinv,
                                              const float* __restrict__ b1,
                                              float* __restrict__ h) {
    int i = blockIdx.x;
    int t = threadIdx.x;
    float di = dinv[i];
    float acc = di * xw1[i * HID + t];          // self-loop (factor di applied at end)
    int s0 = offs[i], s1 = offs[i + 1];
    for (int e = s0; e < s1; e++) {
        int s = csr[e];
        acc += dinv[s] * xw1[s * HID + t];
    }
    float v = di * acc + b1[t];
    h[i * HID + t] = fmaxf(v, 0.0f);
}

// ---------------- GEMM2 (wave per row) + self-loop epilogue into emb ----------------

__global__ __launch_bounds__(256) void k_gemm2(const float* __restrict__ h,
                                               const float* __restrict__ W2,
                                               const float* __restrict__ b2,
                                               const float* __restrict__ dinv,
                                               float* __restrict__ hw2,
                                               float* __restrict__ emb, int n) {
    int w = threadIdx.x >> 6, l = threadIdx.x & 63;
    int row = blockIdx.x * 4 + w;
    if (row >= n) return;
    float4 hv = *(const float4*)&h[row * HID + l * 4];
    // W2 row-major [256][2]; lane l covers k=4l..4l+3 -> floats 8l..8l+7
    float4 w0 = *(const float4*)&W2[l * 8];
    float4 w1 = *(const float4*)&W2[l * 8 + 4];
    float a0 = hv.x * w0.x + hv.y * w0.z + hv.z * w1.x + hv.w * w1.z;
    float a1 = hv.x * w0.y + hv.y * w0.w + hv.z * w1.y + hv.w * w1.w;
    #pragma unroll
    for (int off = 32; off; off >>= 1) {
        a0 += __shfl_down(a0, off);
        a1 += __shfl_down(a1, off);
    }
    if (l == 0) {
        hw2[row * 2] = a0;
        hw2[row * 2 + 1] = a1;
        float di = dinv[row];
        emb[row * 2]     = di * di * a0 + b2[0];
        emb[row * 2 + 1] = di * di * a1 + b2[1];
    }
}

// ---------------- aggregation 2 (wave per node, accumulate into emb) ----------------

__global__ __launch_bounds__(256) void k_agg2(const float* __restrict__ hw2,
                                              const int* __restrict__ offs,
                                              const int* __restrict__ csr,
                                              const float* __restrict__ dinv,
                                              float* __restrict__ emb, int n) {
    int w = threadIdx.x >> 6, l = threadIdx.x & 63;
    int i = blockIdx.x * 4 + w;
    if (i >= n) return;
    int s0 = offs[i], s1 = offs[i + 1];
    float a0 = 0.0f, a1 = 0.0f;
    for (int e = s0 + l; e < s1; e += 64) {
        int s = csr[e];
        float ds = dinv[s];
        a0 += ds * hw2[s * 2];
        a1 += ds * hw2[s * 2 + 1];
    }
    #pragma unroll
    for (int off = 32; off; off >>= 1) {
        a0 += __shfl_down(a0, off);
        a1 += __shfl_down(a1, off);
    }
    if (l == 0) {
        float di = dinv[i];
        emb[i * 2]     += di * a0;   // only this wave touches node i
        emb[i * 2 + 1] += di * a1;
    }
}

// ---------------- q = 1/(1 + 0.5*dist(e_i, e_j)), row-major [n][n] ----------------

__global__ __launch_bounds__(256) void k_q(const float* __restrict__ emb,
                                           float* __restrict__ q, int n) {
    int i = blockIdx.y;
    int j0 = (blockIdx.x * 256 + threadIdx.x) * 4;
    if (j0 >= n) return;
    float2 ei = *(const float2*)&emb[i * 2];
    float4 e01 = *(const float4*)&emb[j0 * 2];
    float4 e23 = *(const float4*)&emb[j0 * 2 + 4];
    float4 out;
    {
        float dx = ei.x - e01.x, dy = ei.y - e01.y;
        out.x = 1.0f / (1.0f + 0.5f * sqrtf(dx * dx + dy * dy));
    }
    {
        float dx = ei.x - e01.z, dy = ei.y - e01.w;
        out.y = 1.0f / (1.0f + 0.5f * sqrtf(dx * dx + dy * dy));
    }
    {
        float dx = ei.x - e23.x, dy = ei.y - e23.y;
        out.z = 1.0f / (1.0f + 0.5f * sqrtf(dx * dx + dy * dy));
    }
    {
        float dx = ei.x - e23.z, dy = ei.y - e23.w;
        out.w = 1.0f / (1.0f + 0.5f * sqrtf(dx * dx + dy * dy));
    }
    *(float4*)&q[(size_t)i * n + j0] = out;
}

// ---------------- launcher ----------------

extern "C" void kernel_launch(void* const* d_in, const int* in_sizes, int n_in,
                              void* d_out, int out_size, void* d_ws, size_t ws_size,
                              hipStream_t stream) {
    const float* features = (const float*)d_in[0];
    const int*   edge_index = (const int*)d_in[1];
    const float* W1 = (const float*)d_in[2];
    const float* b1 = (const float*)d_in[3];
    const float* W2 = (const float*)d_in[4];
    const float* b2 = (const float*)d_in[5];

    const int n = NN;
    const int E = in_sizes[1] / 2;
    const int* src = edge_index;
    const int* dst = edge_index + E;

    char* ws = (char*)d_ws;
    int*   deg    = (int*)ws;   ws += 40000;
    float* dinv   = (float*)ws; ws += 40000;
    int*   offs   = (int*)ws;   ws += 40016;          // n+1, padded to 16B
    int*   cursor = (int*)ws;   ws += 40000;
    int*   csr    = (int*)ws;   ws += (size_t)E * 4;  // 640 KB

    const size_t matElems = (size_t)NN * HID;          // 2.56M floats = 10.24 MB
    const size_t used     = (size_t)(ws - (char*)d_ws);

    // split-K partials are CONTIGUOUS starting at xw1:
    //   part0 = xw1, part1 (aliased by h after reduce), part2+3 (dead after reduce)
    int S = (ws_size >= used + 4 * matElems * 4 + 16) ? 4 : 2;

    float* xw1 = (float*)ws;                 // part0
    float* h   = xw1 + matElems;             // part1 (dead after reduce -> reused as h)
    float* hw2 = xw1 + 2 * matElems;         // part2 region start (dead after reduce)

    float* emb = (float*)d_out;                 // [n,2]
    float* q   = (float*)d_out + (size_t)n * OUT_DIM;  // [n,n]

    k_zero_deg<<<(n + 255) / 256, 256, 0, stream>>>(deg, n);
    k_count<<<(E + 255) / 256, 256, 0, stream>>>(dst, E, deg);
    k_dinv<<<(n + 255) / 256, 256, 0, stream>>>(deg, dinv, n);
    k_scan<<<1, 256, 0, stream>>>(deg, offs, cursor, n, E);
    k_fill<<<(E + 255) / 256, 256, 0, stream>>>(src, dst, E, cursor, csr);

    // split-K GEMM into partial buffers, then reduce into xw1 (part0)
    int kchunk = (IN_DIM + S - 1) / S;
    k_gemm1<<<dim3(HID / G1_BN, (n + G1_BM - 1) / G1_BM, S), 256, 0, stream>>>(
        features, W1, xw1, n, IN_DIM, HID, kchunk);

    int n4 = (int)(matElems / 4);
    k_reduce<<<(n4 + 255) / 256, 256, 0, stream>>>(
        (float4*)xw1, (const float4*)(xw1 + matElems),
        (const float4*)(xw1 + 2 * matElems), (const float4*)(xw1 + 3 * matElems),
        n4, S);

    k_agg1<<<n, HID, 0, stream>>>(xw1, offs, csr, dinv, b1, h);
    k_gemm2<<<(n + 3) / 4, 256, 0, stream>>>(h, W2, b2, dinv, hw2, emb, n);
    k_agg2<<<(n + 3) / 4, 256, 0, stream>>>(hw2, offs, csr, dinv, emb, n);

    k_q<<<dim3((n + 1023) / 1024, n), 256, 0, stream>>>(emb, q, n);
}

// Round 5
// 664.660 us; speedup vs baseline: 2.9823x; 1.0150x over previous
//
#include <hip/hip_runtime.h>
#include <math.h>

#define NN 10000
#define IN_DIM 1000
#define HID 256
#define OUT_DIM 2

// ---------------- degree / CSR build ----------------

__global__ void k_zero_deg(int* deg, int n) {
    int i = blockIdx.x * 256 + threadIdx.x;
    if (i < n) deg[i] = 0;
}

__global__ void k_count(const int* __restrict__ dst, int E, int* __restrict__ deg) {
    int e = blockIdx.x * 256 + threadIdx.x;
    if (e < E) atomicAdd(&deg[dst[e]], 1);
}

__global__ void k_dinv(const int* __restrict__ deg, float* __restrict__ dinv, int n) {
    int i = blockIdx.x * 256 + threadIdx.x;
    if (i < n) dinv[i] = rsqrtf(1.0f + (float)deg[i]);   // self-loop => deg>=1
}

// single-block exclusive scan of deg -> offs, cursor
__global__ void k_scan(const int* __restrict__ deg, int* __restrict__ offs,
                       int* __restrict__ cursor, int n, int E) {
    __shared__ int part[256];
    int t = threadIdx.x;
    int chunk = (n + 255) / 256;
    int lo = t * chunk;
    int hi = lo + chunk; if (hi > n) hi = n;
    int s = 0;
    for (int i = lo; i < hi; i++) s += deg[i];
    part[t] = s;
    __syncthreads();
    if (t == 0) {
        int run = 0;
        for (int i = 0; i < 256; i++) { int tmp = part[i]; part[i] = run; run += tmp; }
    }
    __syncthreads();
    int base = part[t];
    for (int i = lo; i < hi; i++) { offs[i] = base; cursor[i] = base; base += deg[i]; }
    if (t == 0) offs[n] = E;
}

__global__ void k_fill(const int* __restrict__ src, const int* __restrict__ dst, int E,
                       int* __restrict__ cursor, int* __restrict__ csr) {
    int e = blockIdx.x * 256 + threadIdx.x;
    if (e < E) {
        int p = atomicAdd(&cursor[dst[e]], 1);
        csr[p] = src[e];
    }
}

// ---------------- GEMM1 v5: 128x128 tile, 8x8 micro (LDS-balanced), NO vgpr clamp ---
// BK=16, 256 threads (16x16), dbuf LDS, split-K partials (contiguous), k_reduce after.
// Round-1/2 proved this structure correct; their 5 GB traffic was the
// __launch_bounds__(256,4) VGPR=64 clamp spilling acc[8][8] to scratch. No clamp here.

#define G1_BM 128
#define G1_BN 128
#define G1_BK 16
#define G1_LDA (G1_BM + 4)   // 132 floats
#define G1_LDB (G1_BN + 4)

__global__ __launch_bounds__(256) void k_gemm1(const float* __restrict__ A,
                                               const float* __restrict__ B,
                                               float* __restrict__ C,
                                               int M, int K, int N, int kchunk) {
    __shared__ __align__(16) float As[2][G1_BK][G1_LDA];
    __shared__ __align__(16) float Bs[2][G1_BK][G1_LDB];

    const int tid = threadIdx.x;
    const int tx = tid & 15, ty = tid >> 4;
    const int row0 = blockIdx.y * G1_BM, col0 = blockIdx.x * G1_BN;
    const int kbeg = blockIdx.z * kchunk;
    const int kend = (kbeg + kchunk < K) ? (kbeg + kchunk) : K;
    const int T = (kend - kbeg + G1_BK - 1) / G1_BK;

    float* __restrict__ Cp = C + (size_t)blockIdx.z * M * N;

    // staging maps
    const int arow = tid >> 2;          // 0..63 (+64 for r=1)
    const int ak4  = (tid & 3) * 4;     // k offset within tile (0,4,8,12)
    const int bkk  = tid >> 5;          // 0..7 (+8 for r=1)
    const int bcg  = (tid & 31) * 4;    // col offset within tile

    float4 aR[2], bR[2];
    float acc[8][8];
    #pragma unroll
    for (int i = 0; i < 8; i++)
        #pragma unroll
        for (int j = 0; j < 8; j++) acc[i][j] = 0.0f;

    auto loadregs = [&](int t) {
        const int k0 = kbeg + t * G1_BK;
        #pragma unroll
        for (int r = 0; r < 2; r++) {
            int row = row0 + arow + 64 * r;
            int k = k0 + ak4;
            if (row < M && k < kend) aR[r] = *(const float4*)&A[(size_t)row * K + k];
            else                     aR[r] = make_float4(0.f, 0.f, 0.f, 0.f);
        }
        #pragma unroll
        for (int r = 0; r < 2; r++) {
            int k = k0 + bkk + 8 * r;
            if (k < kend) bR[r] = *(const float4*)&B[(size_t)k * N + col0 + bcg];
            else          bR[r] = make_float4(0.f, 0.f, 0.f, 0.f);
        }
    };

    auto storelds = [&](int buf) {
        #pragma unroll
        for (int r = 0; r < 2; r++) {
            int row = arow + 64 * r;
            As[buf][ak4 + 0][row] = aR[r].x;
            As[buf][ak4 + 1][row] = aR[r].y;
            As[buf][ak4 + 2][row] = aR[r].z;
            As[buf][ak4 + 3][row] = aR[r].w;
            *(float4*)&Bs[buf][bkk + 8 * r][bcg] = bR[r];
        }
    };

    loadregs(0);
    storelds(0);
    __syncthreads();

    for (int t = 0; t < T; t++) {
        const int cur = t & 1;
        if (t + 1 < T) loadregs(t + 1);
        #pragma unroll
        for (int kk = 0; kk < G1_BK; kk++) {
            float4 a0 = *(const float4*)&As[cur][kk][4 * ty];
            float4 a1 = *(const float4*)&As[cur][kk][64 + 4 * ty];
            float4 b0 = *(const float4*)&Bs[cur][kk][4 * tx];
            float4 b1 = *(const float4*)&Bs[cur][kk][64 + 4 * tx];
            float av[8] = {a0.x, a0.y, a0.z, a0.w, a1.x, a1.y, a1.z, a1.w};
            float bv[8] = {b0.x, b0.y, b0.z, b0.w, b1.x, b1.y, b1.z, b1.w};
            #pragma unroll
            for (int i = 0; i < 8; i++)
                #pragma unroll
                for (int j = 0; j < 8; j++)
                    acc[i][j] += av[i] * bv[j];
        }
        if (t + 1 < T) storelds((t + 1) & 1);
        __syncthreads();
    }

    // plain vectorized stores into this z's partial buffer
    #pragma unroll
    for (int i = 0; i < 8; i++) {
        int row = row0 + 4 * ty + (i >> 2) * 64 + (i & 3);
        if (row < M) {
            float4 v0 = {acc[i][0], acc[i][1], acc[i][2], acc[i][3]};
            float4 v1 = {acc[i][4], acc[i][5], acc[i][6], acc[i][7]};
            *(float4*)&Cp[(size_t)row * N + col0 + 4 * tx]      = v0;
            *(float4*)&Cp[(size_t)row * N + col0 + 64 + 4 * tx] = v1;
        }
    }
}

// ---------------- reduce split-K partials: p0 += p1 (+ p2 + p3) ----------------

__global__ __launch_bounds__(256) void k_reduce(float4* __restrict__ p0,
                                                const float4* __restrict__ p1,
                                                const float4* __restrict__ p2,
                                                const float4* __restrict__ p3,
                                                int n4, int S) {
    int i = blockIdx.x * 256 + threadIdx.x;
    if (i >= n4) return;
    float4 a = p0[i], b = p1[i];
    float4 r;
    r.x = a.x + b.x; r.y = a.y + b.y; r.z = a.z + b.z; r.w = a.w + b.w;
    if (S == 4) {
        float4 c = p2[i], d = p3[i];
        r.x += c.x + d.x; r.y += c.y + d.y; r.z += c.z + d.z; r.w += c.w + d.w;
    }
    p0[i] = r;
}

// ---------------- aggregation 1 + bias + relu (block per node, thread per dim) -------

__global__ __launch_bounds__(256) void k_agg1(const float* __restrict__ xw1,
                                              const int* __restrict__ offs,
                                              const int* __restrict__ csr,
                                              const float* __restrict__ dinv,
                                              const float* __restrict__ b1,
                                              float* __restrict__ h) {
    int i = blockIdx.x;
    int t = threadIdx.x;
    float di = dinv[i];
    float acc = di * xw1[i * HID + t];          // self-loop (factor di applied at end)
    int s0 = offs[i], s1 = offs[i + 1];
    for (int e = s0; e < s1; e++) {
        int s = csr[e];
        acc += dinv[s] * xw1[s * HID + t];
    }
    float v = di * acc + b1[t];
    h[i * HID + t] = fmaxf(v, 0.0f);
}

// ---------------- GEMM2 (wave per row) + self-loop epilogue into emb ----------------

__global__ __launch_bounds__(256) void k_gemm2(const float* __restrict__ h,
                                               const float* __restrict__ W2,
                                               const float* __restrict__ b2,
                                               const float* __restrict__ dinv,
                                               float* __restrict__ hw2,
                                               float* __restrict__ emb, int n) {
    int w = threadIdx.x >> 6, l = threadIdx.x & 63;
    int row = blockIdx.x * 4 + w;
    if (row >= n) return;
    float4 hv = *(const float4*)&h[row * HID + l * 4];
    // W2 row-major [256][2]; lane l covers k=4l..4l+3 -> floats 8l..8l+7
    float4 w0 = *(const float4*)&W2[l * 8];
    float4 w1 = *(const float4*)&W2[l * 8 + 4];
    float a0 = hv.x * w0.x + hv.y * w0.z + hv.z * w1.x + hv.w * w1.z;
    float a1 = hv.x * w0.y + hv.y * w0.w + hv.z * w1.y + hv.w * w1.w;
    #pragma unroll
    for (int off = 32; off; off >>= 1) {
        a0 += __shfl_down(a0, off);
        a1 += __shfl_down(a1, off);
    }
    if (l == 0) {
        hw2[row * 2] = a0;
        hw2[row * 2 + 1] = a1;
        float di = dinv[row];
        emb[row * 2]     = di * di * a0 + b2[0];
        emb[row * 2 + 1] = di * di * a1 + b2[1];
    }
}

// ---------------- aggregation 2 (wave per node, accumulate into emb) ----------------

__global__ __launch_bounds__(256) void k_agg2(const float* __restrict__ hw2,
                                              const int* __restrict__ offs,
                                              const int* __restrict__ csr,
                                              const float* __restrict__ dinv,
                                              float* __restrict__ emb, int n) {
    int w = threadIdx.x >> 6, l = threadIdx.x & 63;
    int i = blockIdx.x * 4 + w;
    if (i >= n) return;
    int s0 = offs[i], s1 = offs[i + 1];
    float a0 = 0.0f, a1 = 0.0f;
    for (int e = s0 + l; e < s1; e += 64) {
        int s = csr[e];
        float ds = dinv[s];
        a0 += ds * hw2[s * 2];
        a1 += ds * hw2[s * 2 + 1];
    }
    #pragma unroll
    for (int off = 32; off; off >>= 1) {
        a0 += __shfl_down(a0, off);
        a1 += __shfl_down(a1, off);
    }
    if (l == 0) {
        float di = dinv[i];
        emb[i * 2]     += di * a0;   // only this wave touches node i
        emb[i * 2 + 1] += di * a1;
    }
}

// ---------------- q = 1/(1 + 0.5*dist(e_i, e_j)), row-major [n][n] ----------------

__global__ __launch_bounds__(256) void k_q(const float* __restrict__ emb,
                                           float* __restrict__ q, int n) {
    int i = blockIdx.y;
    int j0 = (blockIdx.x * 256 + threadIdx.x) * 4;
    if (j0 >= n) return;
    float2 ei = *(const float2*)&emb[i * 2];
    float4 e01 = *(const float4*)&emb[j0 * 2];
    float4 e23 = *(const float4*)&emb[j0 * 2 + 4];
    float4 out;
    {
        float dx = ei.x - e01.x, dy = ei.y - e01.y;
        out.x = 1.0f / (1.0f + 0.5f * sqrtf(dx * dx + dy * dy));
    }
    {
        float dx = ei.x - e01.z, dy = ei.y - e01.w;
        out.y = 1.0f / (1.0f + 0.5f * sqrtf(dx * dx + dy * dy));
    }
    {
        float dx = ei.x - e23.x, dy = ei.y - e23.y;
        out.z = 1.0f / (1.0f + 0.5f * sqrtf(dx * dx + dy * dy));
    }
    {
        float dx = ei.x - e23.z, dy = ei.y - e23.w;
        out.w = 1.0f / (1.0f + 0.5f * sqrtf(dx * dx + dy * dy));
    }
    *(float4*)&q[(size_t)i * n + j0] = out;
}

// ---------------- launcher ----------------

extern "C" void kernel_launch(void* const* d_in, const int* in_sizes, int n_in,
                              void* d_out, int out_size, void* d_ws, size_t ws_size,
                              hipStream_t stream) {
    const float* features = (const float*)d_in[0];
    const int*   edge_index = (const int*)d_in[1];
    const float* W1 = (const float*)d_in[2];
    const float* b1 = (const float*)d_in[3];
    const float* W2 = (const float*)d_in[4];
    const float* b2 = (const float*)d_in[5];

    const int n = NN;
    const int E = in_sizes[1] / 2;
    const int* src = edge_index;
    const int* dst = edge_index + E;

    char* ws = (char*)d_ws;
    int*   deg    = (int*)ws;   ws += 40000;
    float* dinv   = (float*)ws; ws += 40000;
    int*   offs   = (int*)ws;   ws += 40016;          // n+1, padded to 16B
    int*   cursor = (int*)ws;   ws += 40000;
    int*   csr    = (int*)ws;   ws += (size_t)E * 4;  // 640 KB

    const size_t matElems = (size_t)NN * HID;          // 2.56M floats = 10.24 MB
    const size_t used     = (size_t)(ws - (char*)d_ws);

    // split-K partials are CONTIGUOUS starting at xw1:
    //   part0 = xw1, part1 (aliased by h after reduce), part2+3 (dead after reduce)
    int S = (ws_size >= used + 4 * matElems * 4 + 16) ? 4 : 2;

    float* xw1 = (float*)ws;                 // part0
    float* h   = xw1 + matElems;             // part1 (dead after reduce -> reused as h)
    float* hw2 = xw1 + 2 * matElems;         // part2 region start (dead after reduce)

    float* emb = (float*)d_out;                 // [n,2]
    float* q   = (float*)d_out + (size_t)n * OUT_DIM;  // [n,n]

    k_zero_deg<<<(n + 255) / 256, 256, 0, stream>>>(deg, n);
    k_count<<<(E + 255) / 256, 256, 0, stream>>>(dst, E, deg);
    k_dinv<<<(n + 255) / 256, 256, 0, stream>>>(deg, dinv, n);
    k_scan<<<1, 256, 0, stream>>>(deg, offs, cursor, n, E);
    k_fill<<<(E + 255) / 256, 256, 0, stream>>>(src, dst, E, cursor, csr);

    // split-K GEMM into partial buffers, then reduce into xw1 (part0)
    int kchunk = (IN_DIM + S - 1) / S;
    k_gemm1<<<dim3(HID / G1_BN, (n + G1_BM - 1) / G1_BM, S), 256, 0, stream>>>(
        features, W1, xw1, n, IN_DIM, HID, kchunk);

    int n4 = (int)(matElems / 4);
    k_reduce<<<(n4 + 255) / 256, 256, 0, stream>>>(
        (float4*)xw1, (const float4*)(xw1 + matElems),
        (const float4*)(xw1 + 2 * matElems), (const float4*)(xw1 + 3 * matElems),
        n4, S);

    k_agg1<<<n, HID, 0, stream>>>(xw1, offs, csr, dinv, b1, h);
    k_gemm2<<<(n + 3) / 4, 256, 0, stream>>>(h, W2, b2, dinv, hw2, emb, n);
    k_agg2<<<(n + 3) / 4, 256, 0, stream>>>(hw2, offs, csr, dinv, emb, n);

    k_q<<<dim3((n + 1023) / 1024, n), 256, 0, stream>>>(emb, q, n);
}

// Round 6
// 657.669 us; speedup vs baseline: 3.0140x; 1.0106x over previous
//
#include <hip/hip_runtime.h>
#include <math.h>

#define NN 10000
#define IN_DIM 1000
#define HID 256
#define OUT_DIM 2

// ---------------- degree / CSR build ----------------

__global__ void k_zero_deg(int* deg, int n) {
    int i = blockIdx.x * 256 + threadIdx.x;
    if (i < n) deg[i] = 0;
}

__global__ void k_count(const int* __restrict__ dst, int E, int* __restrict__ deg) {
    int e = blockIdx.x * 256 + threadIdx.x;
    if (e < E) atomicAdd(&deg[dst[e]], 1);
}

__global__ void k_dinv(const int* __restrict__ deg, float* __restrict__ dinv, int n) {
    int i = blockIdx.x * 256 + threadIdx.x;
    if (i < n) dinv[i] = rsqrtf(1.0f + (float)deg[i]);   // self-loop => deg>=1
}

// single-block exclusive scan of deg -> offs, cursor
__global__ void k_scan(const int* __restrict__ deg, int* __restrict__ offs,
                       int* __restrict__ cursor, int n, int E) {
    __shared__ int part[256];
    int t = threadIdx.x;
    int chunk = (n + 255) / 256;
    int lo = t * chunk;
    int hi = lo + chunk; if (hi > n) hi = n;
    int s = 0;
    for (int i = lo; i < hi; i++) s += deg[i];
    part[t] = s;
    __syncthreads();
    if (t == 0) {
        int run = 0;
        for (int i = 0; i < 256; i++) { int tmp = part[i]; part[i] = run; run += tmp; }
    }
    __syncthreads();
    int base = part[t];
    for (int i = lo; i < hi; i++) { offs[i] = base; cursor[i] = base; base += deg[i]; }
    if (t == 0) offs[n] = E;
}

__global__ void k_fill(const int* __restrict__ src, const int* __restrict__ dst, int E,
                       int* __restrict__ cursor, int* __restrict__ csr) {
    int e = blockIdx.x * 256 + threadIdx.x;
    if (e < E) {
        int p = atomicAdd(&cursor[dst[e]], 1);
        csr[p] = src[e];
    }
}

// ---------------- GEMM1 v6: 128x128 tile, 8x8 micro, split-K=8 for occupancy --------
// BK=16, 256 threads (16x16), dbuf LDS, per-z partial buffers, k_reduce after.
// S=8 -> 1264 blocks (~5/CU, LDS 33.8KB caps 4/CU resident) vs S=4's 2.5/CU.

#define G1_BM 128
#define G1_BN 128
#define G1_BK 16
#define G1_LDA (G1_BM + 4)   // 132 floats
#define G1_LDB (G1_BN + 4)

__global__ __launch_bounds__(256) void k_gemm1(const float* __restrict__ A,
                                               const float* __restrict__ B,
                                               float* __restrict__ C,
                                               int M, int K, int N, int kchunk) {
    __shared__ __align__(16) float As[2][G1_BK][G1_LDA];
    __shared__ __align__(16) float Bs[2][G1_BK][G1_LDB];

    const int tid = threadIdx.x;
    const int tx = tid & 15, ty = tid >> 4;
    const int row0 = blockIdx.y * G1_BM, col0 = blockIdx.x * G1_BN;
    const int kbeg = blockIdx.z * kchunk;
    const int kend = (kbeg + kchunk < K) ? (kbeg + kchunk) : K;
    const int T = (kend - kbeg + G1_BK - 1) / G1_BK;

    float* __restrict__ Cp = C + (size_t)blockIdx.z * M * N;

    // staging maps
    const int arow = tid >> 2;          // 0..63 (+64 for r=1)
    const int ak4  = (tid & 3) * 4;     // k offset within tile (0,4,8,12)
    const int bkk  = tid >> 5;          // 0..7 (+8 for r=1)
    const int bcg  = (tid & 31) * 4;    // col offset within tile

    float4 aR[2], bR[2];
    float acc[8][8];
    #pragma unroll
    for (int i = 0; i < 8; i++)
        #pragma unroll
        for (int j = 0; j < 8; j++) acc[i][j] = 0.0f;

    auto loadregs = [&](int t) {
        const int k0 = kbeg + t * G1_BK;
        #pragma unroll
        for (int r = 0; r < 2; r++) {
            int row = row0 + arow + 64 * r;
            int k = k0 + ak4;
            if (row < M && k < kend) aR[r] = *(const float4*)&A[(size_t)row * K + k];
            else                     aR[r] = make_float4(0.f, 0.f, 0.f, 0.f);
        }
        #pragma unroll
        for (int r = 0; r < 2; r++) {
            int k = k0 + bkk + 8 * r;
            if (k < kend) bR[r] = *(const float4*)&B[(size_t)k * N + col0 + bcg];
            else          bR[r] = make_float4(0.f, 0.f, 0.f, 0.f);
        }
    };

    auto storelds = [&](int buf) {
        #pragma unroll
        for (int r = 0; r < 2; r++) {
            int row = arow + 64 * r;
            As[buf][ak4 + 0][row] = aR[r].x;
            As[buf][ak4 + 1][row] = aR[r].y;
            As[buf][ak4 + 2][row] = aR[r].z;
            As[buf][ak4 + 3][row] = aR[r].w;
            *(float4*)&Bs[buf][bkk + 8 * r][bcg] = bR[r];
        }
    };

    loadregs(0);
    storelds(0);
    __syncthreads();

    for (int t = 0; t < T; t++) {
        const int cur = t & 1;
        if (t + 1 < T) loadregs(t + 1);
        #pragma unroll
        for (int kk = 0; kk < G1_BK; kk++) {
            float4 a0 = *(const float4*)&As[cur][kk][4 * ty];
            float4 a1 = *(const float4*)&As[cur][kk][64 + 4 * ty];
            float4 b0 = *(const float4*)&Bs[cur][kk][4 * tx];
            float4 b1 = *(const float4*)&Bs[cur][kk][64 + 4 * tx];
            float av[8] = {a0.x, a0.y, a0.z, a0.w, a1.x, a1.y, a1.z, a1.w};
            float bv[8] = {b0.x, b0.y, b0.z, b0.w, b1.x, b1.y, b1.z, b1.w};
            #pragma unroll
            for (int i = 0; i < 8; i++)
                #pragma unroll
                for (int j = 0; j < 8; j++)
                    acc[i][j] += av[i] * bv[j];
        }
        if (t + 1 < T) storelds((t + 1) & 1);
        __syncthreads();
    }

    // plain vectorized stores into this z's partial buffer
    #pragma unroll
    for (int i = 0; i < 8; i++) {
        int row = row0 + 4 * ty + (i >> 2) * 64 + (i & 3);
        if (row < M) {
            float4 v0 = {acc[i][0], acc[i][1], acc[i][2], acc[i][3]};
            float4 v1 = {acc[i][4], acc[i][5], acc[i][6], acc[i][7]};
            *(float4*)&Cp[(size_t)row * N + col0 + 4 * tx]      = v0;
            *(float4*)&Cp[(size_t)row * N + col0 + 64 + 4 * tx] = v1;
        }
    }
}

// ---------------- reduce split-K partials: p0 += p1..p(S-1) ----------------

__global__ __launch_bounds__(256) void k_reduce(float4* __restrict__ p0,
                                                int n4, int S, size_t strideElems) {
    int i = blockIdx.x * 256 + threadIdx.x;
    if (i >= n4) return;
    const size_t stride4 = strideElems / 4;
    float4 r = p0[i];
    for (int s = 1; s < S; s++) {
        float4 v = p0[i + (size_t)s * stride4];
        r.x += v.x; r.y += v.y; r.z += v.z; r.w += v.w;
    }
    p0[i] = r;
}

// ---------------- aggregation 1 + bias + relu (block per node, thread per dim) -------
// csr indices prefetched 2-deep so the 1KB row gather overlaps the FMA chain.

__global__ __launch_bounds__(256) void k_agg1(const float* __restrict__ xw1,
                                              const int* __restrict__ offs,
                                              const int* __restrict__ csr,
                                              const float* __restrict__ dinv,
                                              const float* __restrict__ b1,
                                              float* __restrict__ h) {
    int i = blockIdx.x;
    int t = threadIdx.x;
    float di = dinv[i];
    float acc = di * xw1[i * HID + t];          // self-loop (factor di applied at end)
    int s0 = offs[i], s1 = offs[i + 1];
    int e = s0;
    int sA = (e < s1) ? csr[e] : 0;
    int sB = (e + 1 < s1) ? csr[e + 1] : 0;
    for (; e + 1 < s1; e += 2) {
        float vA = xw1[sA * HID + t];
        float dA = dinv[sA];
        float vB = xw1[sB * HID + t];
        float dB = dinv[sB];
        sA = (e + 2 < s1) ? csr[e + 2] : 0;
        sB = (e + 3 < s1) ? csr[e + 3] : 0;
        acc += dA * vA;
        acc += dB * vB;
    }
    if (e < s1) {
        acc += dinv[sA] * xw1[sA * HID + t];
    }
    float v = di * acc + b1[t];
    h[i * HID + t] = fmaxf(v, 0.0f);
}

// ---------------- GEMM2 (wave per row) + self-loop epilogue into emb ----------------

__global__ __launch_bounds__(256) void k_gemm2(const float* __restrict__ h,
                                               const float* __restrict__ W2,
                                               const float* __restrict__ b2,
                                               const float* __restrict__ dinv,
                                               float* __restrict__ hw2,
                                               float* __restrict__ emb, int n) {
    int w = threadIdx.x >> 6, l = threadIdx.x & 63;
    int row = blockIdx.x * 4 + w;
    if (row >= n) return;
    float4 hv = *(const float4*)&h[row * HID + l * 4];
    // W2 row-major [256][2]; lane l covers k=4l..4l+3 -> floats 8l..8l+7
    float4 w0 = *(const float4*)&W2[l * 8];
    float4 w1 = *(const float4*)&W2[l * 8 + 4];
    float a0 = hv.x * w0.x + hv.y * w0.z + hv.z * w1.x + hv.w * w1.z;
    float a1 = hv.x * w0.y + hv.y * w0.w + hv.z * w1.y + hv.w * w1.w;
    #pragma unroll
    for (int off = 32; off; off >>= 1) {
        a0 += __shfl_down(a0, off);
        a1 += __shfl_down(a1, off);
    }
    if (l == 0) {
        hw2[row * 2] = a0;
        hw2[row * 2 + 1] = a1;
        float di = dinv[row];
        emb[row * 2]     = di * di * a0 + b2[0];
        emb[row * 2 + 1] = di * di * a1 + b2[1];
    }
}

// ---------------- aggregation 2 (wave per node, accumulate into emb) ----------------

__global__ __launch_bounds__(256) void k_agg2(const float* __restrict__ hw2,
                                              const int* __restrict__ offs,
                                              const int* __restrict__ csr,
                                              const float* __restrict__ dinv,
                                              float* __restrict__ emb, int n) {
    int w = threadIdx.x >> 6, l = threadIdx.x & 63;
    int i = blockIdx.x * 4 + w;
    if (i >= n) return;
    int s0 = offs[i], s1 = offs[i + 1];
    float a0 = 0.0f, a1 = 0.0f;
    for (int e = s0 + l; e < s1; e += 64) {
        int s = csr[e];
        float ds = dinv[s];
        a0 += ds * hw2[s * 2];
        a1 += ds * hw2[s * 2 + 1];
    }
    #pragma unroll
    for (int off = 32; off; off >>= 1) {
        a0 += __shfl_down(a0, off);
        a1 += __shfl_down(a1, off);
    }
    if (l == 0) {
        float di = dinv[i];
        emb[i * 2]     += di * a0;   // only this wave touches node i
        emb[i * 2 + 1] += di * a1;
    }
}

// ---------------- q = 1/(1 + 0.5*dist(e_i, e_j)), row-major [n][n] ----------------

__global__ __launch_bounds__(256) void k_q(const float* __restrict__ emb,
                                           float* __restrict__ q, int n) {
    int i = blockIdx.y;
    int j0 = (blockIdx.x * 256 + threadIdx.x) * 4;
    if (j0 >= n) return;
    float2 ei = *(const float2*)&emb[i * 2];
    float4 e01 = *(const float4*)&emb[j0 * 2];
    float4 e23 = *(const float4*)&emb[j0 * 2 + 4];
    float4 out;
    {
        float dx = ei.x - e01.x, dy = ei.y - e01.y;
        out.x = 1.0f / (1.0f + 0.5f * sqrtf(dx * dx + dy * dy));
    }
    {
        float dx = ei.x - e01.z, dy = ei.y - e01.w;
        out.y = 1.0f / (1.0f + 0.5f * sqrtf(dx * dx + dy * dy));
    }
    {
        float dx = ei.x - e23.x, dy = ei.y - e23.y;
        out.z = 1.0f / (1.0f + 0.5f * sqrtf(dx * dx + dy * dy));
    }
    {
        float dx = ei.x - e23.z, dy = ei.y - e23.w;
        out.w = 1.0f / (1.0f + 0.5f * sqrtf(dx * dx + dy * dy));
    }
    *(float4*)&q[(size_t)i * n + j0] = out;
}

// ---------------- launcher ----------------

extern "C" void kernel_launch(void* const* d_in, const int* in_sizes, int n_in,
                              void* d_out, int out_size, void* d_ws, size_t ws_size,
                              hipStream_t stream) {
    const float* features = (const float*)d_in[0];
    const int*   edge_index = (const int*)d_in[1];
    const float* W1 = (const float*)d_in[2];
    const float* b1 = (const float*)d_in[3];
    const float* W2 = (const float*)d_in[4];
    const float* b2 = (const float*)d_in[5];

    const int n = NN;
    const int E = in_sizes[1] / 2;
    const int* src = edge_index;
    const int* dst = edge_index + E;

    char* ws = (char*)d_ws;
    int*   deg    = (int*)ws;   ws += 40000;
    float* dinv   = (float*)ws; ws += 40000;
    int*   offs   = (int*)ws;   ws += 40016;          // n+1, padded to 16B
    int*   cursor = (int*)ws;   ws += 40000;
    int*   csr    = (int*)ws;   ws += (size_t)E * 4;  // 640 KB

    const size_t matElems = (size_t)NN * HID;          // 2.56M floats = 10.24 MB
    const size_t used     = (size_t)(ws - (char*)d_ws);

    // split-K partials CONTIGUOUS starting at xw1; part1+ dead after k_reduce
    // (h reuses part1 region).
    int S = 2;
    if (ws_size >= used + 8 * matElems * 4 + 16) S = 8;
    else if (ws_size >= used + 4 * matElems * 4 + 16) S = 4;

    float* xw1 = (float*)ws;                 // part0
    float* h   = xw1 + matElems;             // part1 (dead after reduce -> reused as h)
    float* hw2 = xw1 + 2 * matElems;         // part2 region start (dead after reduce)

    float* emb = (float*)d_out;                 // [n,2]
    float* q   = (float*)d_out + (size_t)n * OUT_DIM;  // [n,n]

    k_zero_deg<<<(n + 255) / 256, 256, 0, stream>>>(deg, n);
    k_count<<<(E + 255) / 256, 256, 0, stream>>>(dst, E, deg);
    k_dinv<<<(n + 255) / 256, 256, 0, stream>>>(deg, dinv, n);
    k_scan<<<1, 256, 0, stream>>>(deg, offs, cursor, n, E);
    k_fill<<<(E + 255) / 256, 256, 0, stream>>>(src, dst, E, cursor, csr);

    // split-K GEMM into partial buffers, then reduce into xw1 (part0)
    int kchunk = (IN_DIM + S - 1) / S;
    k_gemm1<<<dim3(HID / G1_BN, (n + G1_BM - 1) / G1_BM, S), 256, 0, stream>>>(
        features, W1, xw1, n, IN_DIM, HID, kchunk);

    int n4 = (int)(matElems / 4);
    k_reduce<<<(n4 + 255) / 256, 256, 0, stream>>>((float4*)xw1, n4, S, matElems);

    k_agg1<<<n, HID, 0, stream>>>(xw1, offs, csr, dinv, b1, h);
    k_gemm2<<<(n + 3) / 4, 256, 0, stream>>>(h, W2, b2, dinv, hw2, emb, n);
    k_agg2<<<(n + 3) / 4, 256, 0, stream>>>(hw2, offs, csr, dinv, emb, n);

    k_q<<<dim3((n + 1023) / 1024, n), 256, 0, stream>>>(emb, q, n);
}